// Round 4
// baseline (380.994 us; speedup 1.0000x reference)
//
#include <hip/hip_runtime.h>
#include <hip/hip_bf16.h>
#include <stdint.h>

#define E_DIM 768
#define S_LEN 2048
#define BATCH 8
#define CT_STRIDE 132   // 128 + 4: makes epilogue b16 LDS scatter conflict-free

typedef __attribute__((ext_vector_type(8))) short short8;   // 8 x bf16 = 4 VGPRs
typedef __attribute__((ext_vector_type(4))) float floatx4;  // MFMA C/D

__device__ __forceinline__ short f2bf(float f) {
    return __builtin_bit_cast(short, __float2bfloat16(f));
}

__device__ __forceinline__ floatx4 mfma16(short8 a, short8 b, floatx4 c) {
    return __builtin_amdgcn_mfma_f32_16x16x32_bf16(a, b, c, 0, 0, 0);
}

// async global->LDS, 16B per lane; LDS dst is wave-uniform base + lane*16,
// global src per-lane free -> XOR swizzle realized by permuting the SOURCE.
__device__ __forceinline__ void glds16(const short* g, short* l) {
    __builtin_amdgcn_global_load_lds(
        (const __attribute__((address_space(1))) void*)g,
        (__attribute__((address_space(3))) void*)l,
        16, 0, 0);
}

// ---------------------------------------------------------------------------
// Shared GEMM core: C[128x128] += A[128xK] * B[128xK]^T, row strides sA/sB.
// 256 threads = 4 waves (2x2), each wave 64x64 via 4x4 frags of 16x16x32.
// BK=64 single-buffered; XOR-swizzled staging -> conflict-free ds_read_b128
// (verified R2: SQ_LDS_BANK_CONFLICT == 0).
// ---------------------------------------------------------------------------
__device__ __forceinline__ void gemm_core(
    const short* __restrict__ Abase, size_t sA,
    const short* __restrict__ Bbase, size_t sB,
    int K,
    short* At, short* Bt,              // 128*64 shorts each (16KB)
    floatx4 acc[4][4])
{
    const int tid  = threadIdx.x;
    const int lane = tid & 63;
    const int wv   = tid >> 6;
    const int lm   = lane & 15, lq = lane >> 4;
    const int rl   = lane >> 3, sl = lane & 7;
    const int usw  = sl ^ rl;                   // swizzled source unit
    const int wm   = (wv & 1) * 64, wn = (wv >> 1) * 64;

    const short* ag = Abase + (size_t)(wv * 32 + rl) * sA + usw * 8;
    const short* bg = Bbase + (size_t)(wv * 32 + rl) * sB + usw * 8;
    short* al = At + wv * 4 * 512;
    short* bl = Bt + wv * 4 * 512;
    const size_t askip = 8 * sA, bskip = 8 * sB;

    for (int kt = 0; kt < K; kt += 64) {
#pragma unroll
        for (int c = 0; c < 4; ++c) glds16(ag + c * askip + kt, al + c * 512);
#pragma unroll
        for (int c = 0; c < 4; ++c) glds16(bg + c * bskip + kt, bl + c * 512);
        __syncthreads();

#pragma unroll
        for (int s = 0; s < 2; ++s) {
            const int u = s * 4 + lq;
            short8 af[4], bf[4];
#pragma unroll
            for (int i = 0; i < 4; ++i) {
                int r = wm + i * 16 + lm;
                af[i] = *(const short8*)&At[((r >> 3) * 64 + (r & 7) * 8 + (u ^ (r & 7))) * 8];
            }
#pragma unroll
            for (int j = 0; j < 4; ++j) {
                int r = wn + j * 16 + lm;
                bf[j] = *(const short8*)&Bt[((r >> 3) * 64 + (r & 7) * 8 + (u ^ (r & 7))) * 8];
            }
#pragma unroll
            for (int i = 0; i < 4; ++i)
#pragma unroll
                for (int j = 0; j < 4; ++j)
                    acc[i][j] = mfma16(af[i], bf[j], acc[i][j]);
        }
        __syncthreads();
    }
}

// --- epilogue helpers: acc -> bf16 LDS tile -> coalesced dwordx4 stores ----
// Normal orientation: Ct[mloc][nloc]. Bank check (b16 writes, stride 132):
// bank = (mloc*66 + nloc>>1) mod 32; lq contributes {0,8,16,24}, lm>>1 {0..7}
// -> all 32 banks, 2 lanes/bank (free).
__device__ __forceinline__ void acc_to_ct(floatx4 acc[4][4], short* Ct) {
    const int lane = threadIdx.x & 63, wv = threadIdx.x >> 6;
    const int lm = lane & 15, lq = lane >> 4;
    const int wm = (wv & 1) * 64, wn = (wv >> 1) * 64;
#pragma unroll
    for (int i = 0; i < 4; ++i)
#pragma unroll
        for (int j = 0; j < 4; ++j)
#pragma unroll
            for (int r = 0; r < 4; ++r)
                Ct[(wm + i * 16 + lq * 4 + r) * CT_STRIDE + wn + j * 16 + lm] =
                    f2bf(acc[i][j][r]);
}

// Transposed orientation: Ct[nloc][mloc]; r is contiguous -> b64 writes.
__device__ __forceinline__ void acc_to_ct_T(floatx4 acc[4][4], short* Ct) {
    const int lane = threadIdx.x & 63, wv = threadIdx.x >> 6;
    const int lm = lane & 15, lq = lane >> 4;
    const int wm = (wv & 1) * 64, wn = (wv >> 1) * 64;
#pragma unroll
    for (int i = 0; i < 4; ++i)
#pragma unroll
        for (int j = 0; j < 4; ++j) {
            short4 h;
            h.x = f2bf(acc[i][j][0]); h.y = f2bf(acc[i][j][1]);
            h.z = f2bf(acc[i][j][2]); h.w = f2bf(acc[i][j][3]);
            *(short4*)&Ct[(wn + j * 16 + lm) * CT_STRIDE + wm + i * 16 + lq * 4] = h;
        }
}

// 2 threads per tile row; each stores 128B contiguous (8 x dwordx4).
__device__ __forceinline__ void ct_writeback(const short* Ct, short* dst,
                                             size_t dstride) {
    __syncthreads();
    const int tid = threadIdx.x;
    const int row = tid >> 1, half = tid & 1;
    const short* src = Ct + row * CT_STRIDE + half * 64;
    short* d = dst + (size_t)row * dstride + half * 64;
#pragma unroll
    for (int u = 0; u < 8; ++u)
        *(uint4*)(d + u * 8) = *(const uint4*)(src + u * 8);
}

// ---------------------------------------------------------------------------
// Per-batch mask compaction: jidx[b][0..nv) = valid col indices, pad dups=0,
// nvp = round-up-128 (min 128).
// ---------------------------------------------------------------------------
__global__ void mask_scan(const int* __restrict__ mask, int* __restrict__ jidx,
                          int* __restrict__ nv, int* __restrict__ nvp) {
    const int b = blockIdx.x;
    const int t = threadIdx.x;
    __shared__ int cnt[256];
    int m[8];
    int c = 0;
#pragma unroll
    for (int k = 0; k < 8; ++k) {
        m[k] = mask[b * S_LEN + t * 8 + k];
        c += (m[k] != 0);
    }
    cnt[t] = c;
    __syncthreads();
    for (int off = 1; off < 256; off <<= 1) {
        int v = (t >= off) ? cnt[t - off] : 0;
        __syncthreads();
        cnt[t] += v;
        __syncthreads();
    }
    int pos = cnt[t] - c;
    const int total = cnt[255];
#pragma unroll
    for (int k = 0; k < 8; ++k)
        if (m[k] != 0) jidx[b * S_LEN + (pos++)] = t * 8 + k;
    __syncthreads();
    for (int i = total + t; i < S_LEN; i += 256) jidx[b * S_LEN + i] = 0;
    if (t == 0) {
        nv[b] = total;
        int p = (total + 127) & ~127;
        if (p < 128) p = 128;
        nvp[b] = p;
    }
}

// ---------------------------------------------------------------------------
__global__ void convert_gather(const float* __restrict__ v, const float* __restrict__ k,
                               const float* __restrict__ q,
                               const int* __restrict__ jidx, const int* __restrict__ nvp,
                               short* __restrict__ xv, short* __restrict__ xk,
                               short* __restrict__ xq) {
    const int z = blockIdx.y, b = blockIdx.z;
    const int r0 = blockIdx.x * 4;
    if (z < 2 && r0 >= nvp[b]) return;
    const float* src = (z == 0) ? v : (z == 1) ? k : q;
    short* dst = (z == 0) ? xv : (z == 1) ? xk : xq;
    const int tid = threadIdx.x;
#pragma unroll
    for (int p = 0; p < 3; ++p) {
        int g   = p * 256 + tid;
        int row = r0 + g / 192;
        int c4  = (g % 192) * 4;
        int srow = (z == 2) ? row : jidx[b * S_LEN + row];
        float4 f = *(const float4*)(src + ((size_t)b * S_LEN + srow) * E_DIM + c4);
        short4 h;
        h.x = f2bf(f.x); h.y = f2bf(f.y); h.z = f2bf(f.z); h.w = f2bf(f.w);
        *(short4*)(dst + ((size_t)b * S_LEN + row) * E_DIM + c4) = h;
    }
}

__global__ void convert_wts(const float* __restrict__ wv, const float* __restrict__ wk,
                            const float* __restrict__ wq, const float* __restrict__ wo,
                            short* __restrict__ o) {
    const int z = blockIdx.y;
    const float* src = (z == 0) ? wv : (z == 1) ? wk : (z == 2) ? wq : wo;
    const float scale = (z == 2) ? (1.0f / (float)E_DIM) : 1.0f;  // fold 1/E into Wq
    size_t i = ((size_t)blockIdx.x * 256 + threadIdx.x) * 4;
    float4 f = *(const float4*)(src + i);
    short4 h;
    h.x = f2bf(f.x * scale); h.y = f2bf(f.y * scale);
    h.z = f2bf(f.z * scale); h.w = f2bf(f.w * scale);
    *(short4*)(o + (size_t)z * E_DIM * E_DIM + i) = h;
}

// ---------------------------------------------------------------------------
// Projections (m-tiles fast in grid -> W tile shared in L2).
// z==0: V compacted -> vt[b][n][i] (transposed); z==1: K compacted; z==2: Q.
// ---------------------------------------------------------------------------
__global__ __launch_bounds__(256, 4) void proj_kernel(
    const short* __restrict__ xv, const short* __restrict__ xk, const short* __restrict__ xq,
    const short* __restrict__ Wb, const int* __restrict__ nvp,
    short* __restrict__ vt, short* __restrict__ kb, short* __restrict__ qb)
{
    const int z  = blockIdx.z;
    const int mt = blockIdx.x;
    const int n0 = blockIdx.y * 128;

    int b = 0, lm0 = 0;
    const short* X;
    if (z == 2) {
        X = xq + (size_t)mt * 128 * E_DIM;
    } else {
        b   = mt >> 4;
        lm0 = (mt & 15) * 128;
        if (lm0 >= nvp[b]) return;
        X = ((z == 0) ? xv : xk) + ((size_t)b * S_LEN + lm0) * E_DIM;
    }
    const short* W = Wb + (size_t)z * E_DIM * E_DIM + (size_t)n0 * E_DIM;

    __shared__ short smem[128 * CT_STRIDE];   // staging (16384) / epilogue Ct
    short* At = smem;
    short* Bt = smem + 8192;

    floatx4 acc[4][4];
#pragma unroll
    for (int i = 0; i < 4; ++i)
#pragma unroll
        for (int j = 0; j < 4; ++j) acc[i][j] = (floatx4){0.f, 0.f, 0.f, 0.f};

    gemm_core(X, E_DIM, W, E_DIM, E_DIM, At, Bt, acc);

    if (z == 0) {        // vt[b][n][i]: transpose epilogue, contiguous along i
        acc_to_ct_T(acc, smem);
        ct_writeback(smem, vt + ((size_t)b * E_DIM + n0) * S_LEN + lm0, S_LEN);
    } else if (z == 1) { // kb[b][i][e]
        acc_to_ct(acc, smem);
        ct_writeback(smem, kb + ((size_t)b * S_LEN + lm0) * E_DIM + n0, E_DIM);
    } else {             // qb[m][e]
        acc_to_ct(acc, smem);
        ct_writeback(smem, qb + (size_t)mt * 128 * E_DIM + n0, E_DIM);
    }
}

// ---------------------------------------------------------------------------
// S = q.k^T over compacted columns; fused exp (no max: |s|<0.5) + rowsum.
// ---------------------------------------------------------------------------
__global__ __launch_bounds__(256, 4) void score_kernel(
    const short* __restrict__ qb, const short* __restrict__ kb,
    const int* __restrict__ nv, const int* __restrict__ nvp,
    short* __restrict__ P, float* __restrict__ rowsum)
{
    const int b  = blockIdx.z;
    const int m0 = blockIdx.x * 128;
    const int n0 = blockIdx.y * 128;
    if (n0 >= nvp[b]) return;

    __shared__ short smem[128 * CT_STRIDE];
    short* At = smem;
    short* Bt = smem + 8192;

    floatx4 acc[4][4];
#pragma unroll
    for (int i = 0; i < 4; ++i)
#pragma unroll
        for (int j = 0; j < 4; ++j) acc[i][j] = (floatx4){0.f, 0.f, 0.f, 0.f};

    gemm_core(qb + ((size_t)b * S_LEN + m0) * E_DIM, E_DIM,
              kb + ((size_t)b * S_LEN + n0) * E_DIM, E_DIM, E_DIM, At, Bt, acc);

    const int lane = threadIdx.x & 63, wv = threadIdx.x >> 6;
    const int lm = lane & 15, lq = lane >> 4;
    const int wm = (wv & 1) * 64, wn = (wv >> 1) * 64;
    const int nvb = nv[b];

    float rsum[4][4];
#pragma unroll
    for (int i = 0; i < 4; ++i)
#pragma unroll
        for (int r = 0; r < 4; ++r) rsum[i][r] = 0.f;

#pragma unroll
    for (int j = 0; j < 4; ++j) {
        bool valid = (n0 + wn + j * 16 + lm) < nvb;
#pragma unroll
        for (int i = 0; i < 4; ++i)
#pragma unroll
            for (int r = 0; r < 4; ++r) {
                float p = valid ? __expf(acc[i][j][r]) : 0.0f;
                acc[i][j][r] = p;
                rsum[i][r] += p;
            }
    }

    acc_to_ct(acc, smem);
    ct_writeback(smem, P + (size_t)b * S_LEN * S_LEN + (size_t)m0 * S_LEN + n0,
                 S_LEN);

#pragma unroll
    for (int i = 0; i < 4; ++i)
#pragma unroll
        for (int r = 0; r < 4; ++r) {
            float v = rsum[i][r];
            v += __shfl_xor(v, 1);
            v += __shfl_xor(v, 2);
            v += __shfl_xor(v, 4);
            v += __shfl_xor(v, 8);
            if (lm == 0)
                atomicAdd(&rowsum[b * S_LEN + m0 + wm + i * 16 + lq * 4 + r], v);
        }
}

// ---------------------------------------------------------------------------
// O = (P.V)/rowsum over compacted K (nvp[b]) -> abuf bf16.
// ---------------------------------------------------------------------------
__global__ __launch_bounds__(256, 4) void pv_kernel(
    const short* __restrict__ P, const short* __restrict__ vt,
    const float* __restrict__ rowsum, const int* __restrict__ nvp,
    short* __restrict__ abuf)
{
    const int b  = blockIdx.z;
    const int m0 = blockIdx.x * 128;
    const int n0 = blockIdx.y * 128;

    __shared__ short smem[128 * CT_STRIDE];
    short* At = smem;
    short* Bt = smem + 8192;

    floatx4 acc[4][4];
#pragma unroll
    for (int i = 0; i < 4; ++i)
#pragma unroll
        for (int j = 0; j < 4; ++j) acc[i][j] = (floatx4){0.f, 0.f, 0.f, 0.f};

    gemm_core(P + (size_t)b * S_LEN * S_LEN + (size_t)m0 * S_LEN, S_LEN,
              vt + ((size_t)b * E_DIM + n0) * S_LEN, S_LEN, nvp[b], At, Bt, acc);

    const int lane = threadIdx.x & 63, wv = threadIdx.x >> 6;
    const int lq = lane >> 4;
    const int wm = (wv & 1) * 64;

#pragma unroll
    for (int i = 0; i < 4; ++i) {
        int mbase = m0 + wm + i * 16 + lq * 4;
#pragma unroll
        for (int r = 0; r < 4; ++r) {
            float inv = 1.0f / rowsum[b * S_LEN + mbase + r];
#pragma unroll
            for (int j = 0; j < 4; ++j) acc[i][j][r] *= inv;
        }
    }

    acc_to_ct(acc, smem);
    ct_writeback(smem, abuf + ((size_t)b * S_LEN + m0) * E_DIM + n0, E_DIM);
}

// ---------------------------------------------------------------------------
// out[m,n] = A[m,:].Wo[n,:] + bo[n]  (fp32 out, 64B segments - kept direct).
// ---------------------------------------------------------------------------
__global__ __launch_bounds__(256, 3) void out_kernel(
    const short* __restrict__ A, const short* __restrict__ W,
    const float* __restrict__ bias, float* __restrict__ Y)
{
    const int m0 = blockIdx.x * 128;
    const int n0 = blockIdx.y * 128;

    __shared__ short At[128 * 64];
    __shared__ short Bt[128 * 64];

    floatx4 acc[4][4];
#pragma unroll
    for (int i = 0; i < 4; ++i)
#pragma unroll
        for (int j = 0; j < 4; ++j) acc[i][j] = (floatx4){0.f, 0.f, 0.f, 0.f};

    gemm_core(A + (size_t)m0 * E_DIM, E_DIM, W + (size_t)n0 * E_DIM, E_DIM,
              E_DIM, At, Bt, acc);

    const int lane = threadIdx.x & 63, wv = threadIdx.x >> 6;
    const int lm = lane & 15, lq = lane >> 4;
    const int wm = (wv & 1) * 64, wn = (wv >> 1) * 64;

#pragma unroll
    for (int j = 0; j < 4; ++j) {
        int n = n0 + wn + j * 16 + lm;
        float bv = bias[n];
#pragma unroll
        for (int i = 0; i < 4; ++i)
#pragma unroll
            for (int r = 0; r < 4; ++r) {
                int m = m0 + wm + i * 16 + lq * 4 + r;
                Y[(size_t)m * E_DIM + n] = acc[i][j][r] + bv;
            }
    }
}

// ---------------------------------------------------------------------------
extern "C" void kernel_launch(void* const* d_in, const int* in_sizes, int n_in,
                              void* d_out, int out_size, void* d_ws, size_t ws_size,
                              hipStream_t stream) {
    const float* value = (const float*)d_in[0];
    const float* key   = (const float*)d_in[1];
    const float* query = (const float*)d_in[2];
    const int*   mask  = (const int*)d_in[3];
    const float* Wv    = (const float*)d_in[4];
    const float* Wk    = (const float*)d_in[5];
    const float* Wq    = (const float*)d_in[6];
    const float* Wo    = (const float*)d_in[7];
    const float* bo    = (const float*)d_in[8];
    float* out = (float*)d_out;

    const size_t WN  = (size_t)E_DIM * E_DIM;
    const size_t ACT = (size_t)BATCH * S_LEN * E_DIM;

    short* Wb  = (short*)d_ws;
    short* xv  = Wb + 4 * WN;
    short* xk  = xv + ACT;
    short* xq  = xk + ACT;
    short* vt  = xq + ACT;
    short* kb  = vt + ACT;
    short* qb  = kb + ACT;
    float* rowsum = (float*)(qb + ACT);
    int*   nv  = (int*)(rowsum + (size_t)BATCH * S_LEN);
    int*   nvp = nv + BATCH;
    int*   jidx = (int*)qb;            // consumed before proj writes qb
    short* P    = xv;                  // overlays dead xv/xk
    short* abuf = qb;                  // overlays dead qb

    hipMemsetAsync(rowsum, 0, (size_t)BATCH * S_LEN * sizeof(float), stream);

    mask_scan<<<BATCH, 256, 0, stream>>>(mask, jidx, nv, nvp);
    convert_wts<<<dim3(576, 4), 256, 0, stream>>>(Wv, Wk, Wq, Wo, Wb);
    convert_gather<<<dim3(512, 3, 8), 256, 0, stream>>>(value, key, query,
                                                        jidx, nvp, xv, xk, xq);

    proj_kernel<<<dim3(128, 6, 3), 256, 0, stream>>>(xv, xk, xq, Wb, nvp,
                                                     vt, kb, qb);

    score_kernel<<<dim3(16, 16, 8), 256, 0, stream>>>(qb, kb, nv, nvp, P, rowsum);

    pv_kernel<<<dim3(16, 6, 8), 256, 0, stream>>>(P, vt, rowsum, nvp, abuf);

    out_kernel<<<dim3(128, 6), 256, 0, stream>>>(abuf, Wb + 3 * WN, bo, out);
}

// Round 5
// 337.497 us; speedup vs baseline: 1.1289x; 1.1289x over previous
//
#include <hip/hip_runtime.h>
#include <hip/hip_bf16.h>
#include <stdint.h>

#define E_DIM 768
#define S_LEN 2048
#define BATCH 8

typedef __attribute__((ext_vector_type(8))) short short8;   // 8 x bf16 = 4 VGPRs
typedef __attribute__((ext_vector_type(4))) float floatx4;  // MFMA C/D

__device__ __forceinline__ short f2bf(float f) {
    return __builtin_bit_cast(short, __float2bfloat16(f));
}

__device__ __forceinline__ floatx4 mfma16(short8 a, short8 b, floatx4 c) {
    return __builtin_amdgcn_mfma_f32_16x16x32_bf16(a, b, c, 0, 0, 0);
}

// async global->LDS, 16B per lane; LDS dst is wave-uniform base + lane*16,
// global src per-lane free -> XOR swizzle realized by permuting the SOURCE.
__device__ __forceinline__ void glds16(const short* g, short* l) {
    __builtin_amdgcn_global_load_lds(
        (const __attribute__((address_space(1))) void*)g,
        (__attribute__((address_space(3))) void*)l,
        16, 0, 0);
}

// ---------------------------------------------------------------------------
// Shared GEMM core: C[128x128] += A[128xK] * B[128xK]^T, row strides sA/sB.
// 256 threads = 4 waves (2x2), each wave 64x64 via 4x4 frags of 16x16x32.
// BK=64 single-buffered; XOR-swizzled staging -> conflict-free ds_read_b128
// (verified R2/R3: SQ_LDS_BANK_CONFLICT == 0). R4 note: LDS-epilogue variant
// REGRESSED (347->381us, +22MB HBM fetch) -- direct scalar epilogue stores
// are absorbed by L2 write-combining; keep them.
// ---------------------------------------------------------------------------
__device__ __forceinline__ void gemm_core(
    const short* __restrict__ Abase, size_t sA,
    const short* __restrict__ Bbase, size_t sB,
    int K,
    short* At, short* Bt,              // 128*64 shorts each (16KB)
    floatx4 acc[4][4])
{
    const int tid  = threadIdx.x;
    const int lane = tid & 63;
    const int wv   = tid >> 6;
    const int lm   = lane & 15, lq = lane >> 4;
    const int rl   = lane >> 3, sl = lane & 7;
    const int usw  = sl ^ rl;                   // swizzled source unit
    const int wm   = (wv & 1) * 64, wn = (wv >> 1) * 64;

    const short* ag = Abase + (size_t)(wv * 32 + rl) * sA + usw * 8;
    const short* bg = Bbase + (size_t)(wv * 32 + rl) * sB + usw * 8;
    short* al = At + wv * 4 * 512;
    short* bl = Bt + wv * 4 * 512;
    const size_t askip = 8 * sA, bskip = 8 * sB;

    for (int kt = 0; kt < K; kt += 64) {
#pragma unroll
        for (int c = 0; c < 4; ++c) glds16(ag + c * askip + kt, al + c * 512);
#pragma unroll
        for (int c = 0; c < 4; ++c) glds16(bg + c * bskip + kt, bl + c * 512);
        __syncthreads();

#pragma unroll
        for (int s = 0; s < 2; ++s) {
            const int u = s * 4 + lq;
            short8 af[4], bf[4];
#pragma unroll
            for (int i = 0; i < 4; ++i) {
                int r = wm + i * 16 + lm;
                af[i] = *(const short8*)&At[((r >> 3) * 64 + (r & 7) * 8 + (u ^ (r & 7))) * 8];
            }
#pragma unroll
            for (int j = 0; j < 4; ++j) {
                int r = wn + j * 16 + lm;
                bf[j] = *(const short8*)&Bt[((r >> 3) * 64 + (r & 7) * 8 + (u ^ (r & 7))) * 8];
            }
#pragma unroll
            for (int i = 0; i < 4; ++i)
#pragma unroll
                for (int j = 0; j < 4; ++j)
                    acc[i][j] = mfma16(af[i], bf[j], acc[i][j]);
        }
        __syncthreads();
    }
}

// ---------------------------------------------------------------------------
// prep: fused front-end (one dispatch replaces convert_wts + q-convert +
// mask_scan + rowsum memset). Flat grid partitioned by block ranges:
//   [0,2304):     weight fp32->bf16 (z = blk/576; Wq scaled by 1/E)
//   [2304,6400):  query fp32->bf16, 4 rows/block
//   [6400,6416):  rowsum zero (16 blocks x 4KB)
//   [6416,6424):  per-batch mask compaction -> jidx, nv, nvp
// ---------------------------------------------------------------------------
__global__ void prep(const float* __restrict__ Wv, const float* __restrict__ Wk,
                     const float* __restrict__ Wq, const float* __restrict__ Wo,
                     const float* __restrict__ query, const int* __restrict__ mask,
                     short* __restrict__ Wb, short* __restrict__ xq,
                     float* __restrict__ rowsum,
                     int* __restrict__ jidx, int* __restrict__ nv,
                     int* __restrict__ nvp)
{
    __shared__ int cnt[256];
    const int blk = blockIdx.x;
    const int t   = threadIdx.x;

    if (blk < 2304) {                       // ---- weight convert
        const int z = blk / 576;
        const float* src = (z == 0) ? Wv : (z == 1) ? Wk : (z == 2) ? Wq : Wo;
        const float scale = (z == 2) ? (1.0f / (float)E_DIM) : 1.0f;
        size_t i = ((size_t)(blk - z * 576) * 256 + t) * 4;
        float4 f = *(const float4*)(src + i);
        short4 h;
        h.x = f2bf(f.x * scale); h.y = f2bf(f.y * scale);
        h.z = f2bf(f.z * scale); h.w = f2bf(f.w * scale);
        *(short4*)(Wb + (size_t)z * E_DIM * E_DIM + i) = h;
    } else if (blk < 6400) {                // ---- query convert, 4 rows/block
        const int g0 = blk - 2304;          // 0..4095
        const size_t base = (size_t)g0 * 4 * E_DIM;   // rows are contiguous over b
#pragma unroll
        for (int p = 0; p < 3; ++p) {
            size_t i = base + ((size_t)p * 256 + t) * 4;
            float4 f = *(const float4*)(query + i);
            short4 h;
            h.x = f2bf(f.x); h.y = f2bf(f.y); h.z = f2bf(f.z); h.w = f2bf(f.w);
            *(short4*)(xq + i) = h;
        }
    } else if (blk < 6416) {                // ---- rowsum zero
        const int g0 = blk - 6400;
        *(float4*)(rowsum + ((size_t)g0 * 256 + t) * 4) = (float4){0.f, 0.f, 0.f, 0.f};
    } else {                                // ---- mask compaction
        const int b = blk - 6416;
        int m[8];
        int c = 0;
#pragma unroll
        for (int k = 0; k < 8; ++k) {
            m[k] = mask[b * S_LEN + t * 8 + k];
            c += (m[k] != 0);
        }
        cnt[t] = c;
        __syncthreads();
        for (int off = 1; off < 256; off <<= 1) {
            int v = (t >= off) ? cnt[t - off] : 0;
            __syncthreads();
            cnt[t] += v;
            __syncthreads();
        }
        int pos = cnt[t] - c;
        const int total = cnt[255];
#pragma unroll
        for (int k = 0; k < 8; ++k)
            if (m[k] != 0) jidx[b * S_LEN + (pos++)] = t * 8 + k;
        __syncthreads();
        for (int i = total + t; i < S_LEN; i += 256) jidx[b * S_LEN + i] = 0;
        if (t == 0) {
            nv[b] = total;
            int p = (total + 127) & ~127;
            if (p < 128) p = 128;
            nvp[b] = p;
        }
    }
}

// ---------------------------------------------------------------------------
// gather+convert value/key rows through jidx (compacted). 4 rows/block.
// ---------------------------------------------------------------------------
__global__ void gather_vk(const float* __restrict__ v, const float* __restrict__ k,
                          const int* __restrict__ jidx, const int* __restrict__ nvp,
                          short* __restrict__ xv, short* __restrict__ xk) {
    const int z = blockIdx.y, b = blockIdx.z;
    const int r0 = blockIdx.x * 4;
    if (r0 >= nvp[b]) return;
    const float* src = (z == 0) ? v : k;
    short* dst = (z == 0) ? xv : xk;
    const int tid = threadIdx.x;
#pragma unroll
    for (int p = 0; p < 3; ++p) {
        int g   = p * 256 + tid;
        int row = r0 + g / 192;
        int c4  = (g % 192) * 4;
        int srow = jidx[b * S_LEN + row];
        float4 f = *(const float4*)(src + ((size_t)b * S_LEN + srow) * E_DIM + c4);
        short4 h;
        h.x = f2bf(f.x); h.y = f2bf(f.y); h.z = f2bf(f.z); h.w = f2bf(f.w);
        *(short4*)(dst + ((size_t)b * S_LEN + row) * E_DIM + c4) = h;
    }
}

// ---------------------------------------------------------------------------
// Projections (m-tiles fast in grid -> W tile shared in L2).
// z==0: V compacted -> vt[b][n][i] (transposed); z==1: K compacted; z==2: Q.
// ---------------------------------------------------------------------------
__global__ __launch_bounds__(256, 3) void proj_kernel(
    const short* __restrict__ xv, const short* __restrict__ xk, const short* __restrict__ xq,
    const short* __restrict__ Wb, const int* __restrict__ nvp,
    short* __restrict__ vt, short* __restrict__ kb, short* __restrict__ qb)
{
    const int z  = blockIdx.z;
    const int mt = blockIdx.x;
    const int n0 = blockIdx.y * 128;

    int b = 0, lm0 = 0;
    const short* X;
    if (z == 2) {
        X = xq + (size_t)mt * 128 * E_DIM;
    } else {
        b   = mt >> 4;
        lm0 = (mt & 15) * 128;
        if (lm0 >= nvp[b]) return;
        X = ((z == 0) ? xv : xk) + ((size_t)b * S_LEN + lm0) * E_DIM;
    }
    const short* W = Wb + (size_t)z * E_DIM * E_DIM + (size_t)n0 * E_DIM;

    __shared__ short At[128 * 64];
    __shared__ short Bt[128 * 64];

    floatx4 acc[4][4];
#pragma unroll
    for (int i = 0; i < 4; ++i)
#pragma unroll
        for (int j = 0; j < 4; ++j) acc[i][j] = (floatx4){0.f, 0.f, 0.f, 0.f};

    gemm_core(X, E_DIM, W, E_DIM, E_DIM, At, Bt, acc);

    const int lane = threadIdx.x & 63, wv = threadIdx.x >> 6;
    const int lm = lane & 15, lq = lane >> 4;
    const int wm = (wv & 1) * 64, wn = (wv >> 1) * 64;

    if (z == 0) {        // vt[b][n][i]
#pragma unroll
        for (int i = 0; i < 4; ++i)
#pragma unroll
            for (int r = 0; r < 4; ++r) {
                int li = lm0 + wm + i * 16 + lq * 4 + r;
#pragma unroll
                for (int j = 0; j < 4; ++j) {
                    int n = n0 + wn + j * 16 + lm;
                    vt[((size_t)b * E_DIM + n) * S_LEN + li] = f2bf(acc[i][j][r]);
                }
            }
    } else if (z == 1) { // kb[b][i][e]
#pragma unroll
        for (int i = 0; i < 4; ++i)
#pragma unroll
            for (int r = 0; r < 4; ++r) {
                int li = lm0 + wm + i * 16 + lq * 4 + r;
#pragma unroll
                for (int j = 0; j < 4; ++j) {
                    int n = n0 + wn + j * 16 + lm;
                    kb[((size_t)b * S_LEN + li) * E_DIM + n] = f2bf(acc[i][j][r]);
                }
            }
    } else {             // qb[m][e]
#pragma unroll
        for (int i = 0; i < 4; ++i)
#pragma unroll
            for (int r = 0; r < 4; ++r) {
                int m = mt * 128 + wm + i * 16 + lq * 4 + r;
#pragma unroll
                for (int j = 0; j < 4; ++j) {
                    int n = n0 + wn + j * 16 + lm;
                    qb[(size_t)m * E_DIM + n] = f2bf(acc[i][j][r]);
                }
            }
    }
}

// ---------------------------------------------------------------------------
// S = q.k^T over compacted columns; fused exp (no max: |s|<0.5) + rowsum.
// ---------------------------------------------------------------------------
__global__ __launch_bounds__(256, 3) void score_kernel(
    const short* __restrict__ qb, const short* __restrict__ kb,
    const int* __restrict__ nv, const int* __restrict__ nvp,
    short* __restrict__ P, float* __restrict__ rowsum)
{
    const int b  = blockIdx.z;
    const int m0 = blockIdx.x * 128;
    const int n0 = blockIdx.y * 128;
    if (n0 >= nvp[b]) return;

    __shared__ short At[128 * 64];
    __shared__ short Bt[128 * 64];

    floatx4 acc[4][4];
#pragma unroll
    for (int i = 0; i < 4; ++i)
#pragma unroll
        for (int j = 0; j < 4; ++j) acc[i][j] = (floatx4){0.f, 0.f, 0.f, 0.f};

    gemm_core(qb + ((size_t)b * S_LEN + m0) * E_DIM, E_DIM,
              kb + ((size_t)b * S_LEN + n0) * E_DIM, E_DIM, E_DIM, At, Bt, acc);

    const int lane = threadIdx.x & 63, wv = threadIdx.x >> 6;
    const int lm = lane & 15, lq = lane >> 4;
    const int wm = (wv & 1) * 64, wn = (wv >> 1) * 64;
    const int nvb = nv[b];

    float rsum[4][4];
#pragma unroll
    for (int i = 0; i < 4; ++i)
#pragma unroll
        for (int r = 0; r < 4; ++r) rsum[i][r] = 0.f;

    const size_t Pbb = (size_t)b * S_LEN * S_LEN;
#pragma unroll
    for (int j = 0; j < 4; ++j) {
        int n = n0 + wn + j * 16 + lm;
        bool valid = n < nvb;
#pragma unroll
        for (int i = 0; i < 4; ++i) {
            int mbase = m0 + wm + i * 16 + lq * 4;
#pragma unroll
            for (int r = 0; r < 4; ++r) {
                float p = valid ? __expf(acc[i][j][r]) : 0.0f;
                rsum[i][r] += p;
                P[Pbb + (size_t)(mbase + r) * S_LEN + n] = f2bf(p);
            }
        }
    }
#pragma unroll
    for (int i = 0; i < 4; ++i)
#pragma unroll
        for (int r = 0; r < 4; ++r) {
            float v = rsum[i][r];
            v += __shfl_xor(v, 1);
            v += __shfl_xor(v, 2);
            v += __shfl_xor(v, 4);
            v += __shfl_xor(v, 8);
            if (lm == 0)
                atomicAdd(&rowsum[b * S_LEN + m0 + wm + i * 16 + lq * 4 + r], v);
        }
}

// ---------------------------------------------------------------------------
// O = (P.V)/rowsum over compacted K (nvp[b]) -> abuf bf16.
// ---------------------------------------------------------------------------
__global__ __launch_bounds__(256, 3) void pv_kernel(
    const short* __restrict__ P, const short* __restrict__ vt,
    const float* __restrict__ rowsum, const int* __restrict__ nvp,
    short* __restrict__ abuf)
{
    const int b  = blockIdx.z;
    const int m0 = blockIdx.x * 128;
    const int n0 = blockIdx.y * 128;

    __shared__ short At[128 * 64];
    __shared__ short Bt[128 * 64];

    floatx4 acc[4][4];
#pragma unroll
    for (int i = 0; i < 4; ++i)
#pragma unroll
        for (int j = 0; j < 4; ++j) acc[i][j] = (floatx4){0.f, 0.f, 0.f, 0.f};

    gemm_core(P + (size_t)b * S_LEN * S_LEN + (size_t)m0 * S_LEN, S_LEN,
              vt + ((size_t)b * E_DIM + n0) * S_LEN, S_LEN, nvp[b], At, Bt, acc);

    const int lane = threadIdx.x & 63, wv = threadIdx.x >> 6;
    const int lm = lane & 15, lq = lane >> 4;
    const int wm = (wv & 1) * 64, wn = (wv >> 1) * 64;

#pragma unroll
    for (int i = 0; i < 4; ++i) {
        int mbase = m0 + wm + i * 16 + lq * 4;
#pragma unroll
        for (int r = 0; r < 4; ++r) {
            float inv = 1.0f / rowsum[b * S_LEN + mbase + r];
            size_t ob = ((size_t)b * S_LEN + mbase + r) * E_DIM;
#pragma unroll
            for (int j = 0; j < 4; ++j) {
                int n = n0 + wn + j * 16 + lm;
                abuf[ob + n] = f2bf(acc[i][j][r] * inv);
            }
        }
    }
}

// ---------------------------------------------------------------------------
// out[m,n] = A[m,:].Wo[n,:] + bo[n]  (fp32 out). m-fast grid.
// ---------------------------------------------------------------------------
__global__ __launch_bounds__(256, 3) void out_kernel(
    const short* __restrict__ A, const short* __restrict__ W,
    const float* __restrict__ bias, float* __restrict__ Y)
{
    const int m0 = blockIdx.x * 128;
    const int n0 = blockIdx.y * 128;

    __shared__ short At[128 * 64];
    __shared__ short Bt[128 * 64];

    floatx4 acc[4][4];
#pragma unroll
    for (int i = 0; i < 4; ++i)
#pragma unroll
        for (int j = 0; j < 4; ++j) acc[i][j] = (floatx4){0.f, 0.f, 0.f, 0.f};

    gemm_core(A + (size_t)m0 * E_DIM, E_DIM, W + (size_t)n0 * E_DIM, E_DIM,
              E_DIM, At, Bt, acc);

    const int lane = threadIdx.x & 63, wv = threadIdx.x >> 6;
    const int lm = lane & 15, lq = lane >> 4;
    const int wm = (wv & 1) * 64, wn = (wv >> 1) * 64;

#pragma unroll
    for (int j = 0; j < 4; ++j) {
        int n = n0 + wn + j * 16 + lm;
        float bv = bias[n];
#pragma unroll
        for (int i = 0; i < 4; ++i)
#pragma unroll
            for (int r = 0; r < 4; ++r) {
                int m = m0 + wm + i * 16 + lq * 4 + r;
                Y[(size_t)m * E_DIM + n] = acc[i][j][r] + bv;
            }
    }
}

// ---------------------------------------------------------------------------
extern "C" void kernel_launch(void* const* d_in, const int* in_sizes, int n_in,
                              void* d_out, int out_size, void* d_ws, size_t ws_size,
                              hipStream_t stream) {
    const float* value = (const float*)d_in[0];
    const float* key   = (const float*)d_in[1];
    const float* query = (const float*)d_in[2];
    const int*   mask  = (const int*)d_in[3];
    const float* Wv    = (const float*)d_in[4];
    const float* Wk    = (const float*)d_in[5];
    const float* Wq    = (const float*)d_in[6];
    const float* Wo    = (const float*)d_in[7];
    const float* bo    = (const float*)d_in[8];
    float* out = (float*)d_out;

    const size_t WN  = (size_t)E_DIM * E_DIM;
    const size_t ACT = (size_t)BATCH * S_LEN * E_DIM;

    short* Wb  = (short*)d_ws;
    short* xv  = Wb + 4 * WN;
    short* xk  = xv + ACT;
    short* xq  = xk + ACT;
    short* vt  = xq + ACT;
    short* kb  = vt + ACT;
    short* qb  = kb + ACT;
    float* rowsum = (float*)(qb + ACT);
    int*   nv  = (int*)(rowsum + (size_t)BATCH * S_LEN);
    int*   nvp = nv + BATCH;
    int*   jidx = (int*)qb;            // consumed by gather before proj writes qb
    short* P    = xv;                  // overlays dead xv/xk
    short* abuf = qb;                  // overlays dead qb

    // 6 dispatches total (was 9): prep fuses wconv+qconv+mask_scan+memset.
    prep<<<6424, 256, 0, stream>>>(Wv, Wk, Wq, Wo, query, mask,
                                   Wb, xq, rowsum, jidx, nv, nvp);

    gather_vk<<<dim3(512, 2, 8), 256, 0, stream>>>(value, key, jidx, nvp, xv, xk);

    proj_kernel<<<dim3(128, 6, 3), 256, 0, stream>>>(xv, xk, xq, Wb, nvp,
                                                     vt, kb, qb);

    score_kernel<<<dim3(16, 16, 8), 256, 0, stream>>>(qb, kb, nv, nvp, P, rowsum);

    pv_kernel<<<dim3(16, 6, 8), 256, 0, stream>>>(P, vt, rowsum, nvp, abuf);

    out_kernel<<<dim3(128, 6), 256, 0, stream>>>(abuf, Wb + 3 * WN, bo, out);
}